// Round 5
// baseline (365.092 us; speedup 1.0000x reference)
//
#include <hip/hip_runtime.h>
#include <type_traits>

#define N_TOK 65536
#define K_CODE 8192
#define D_DIM 64

constexpr float DECAY = 0.9f;
constexpr float OMD = 0.1f;   // 1 - DECAY
constexpr float EPS = 1e-5f;

// ---- output layout (floats), per reference return order ----
constexpr int OUT_QE = 0;
constexpr int OUT_W  = 1;
constexpr int OUT_CS = 1 + K_CODE * D_DIM;
constexpr int OUT_EA = OUT_CS + K_CODE;

// ---- workspace layout (floats) ----
constexpr int WS_QE     = 0;
constexpr int WS_NSUM   = 1;
constexpr int WS_COUNTS = 16;
constexpr int WS_EMBSUM = WS_COUNTS + K_CODE;
constexpr int WS_WHI    = WS_EMBSUM + K_CODE * D_DIM;   // ushort[K*64] bf16 hi
constexpr int WS_WLO    = WS_WHI + K_CODE * D_DIM / 2;  // ushort[K*64] bf16 lo
constexpr int WS_CNP    = WS_WLO + K_CODE * D_DIM / 2;  // uint[K]: bf16(0.5*cn) hi|lo<<16
constexpr int WS_ZERO   = WS_WHI;                       // floats to memset

typedef __attribute__((ext_vector_type(16))) float floatx16;
typedef __attribute__((ext_vector_type(8)))  short short8;
typedef __attribute__((ext_vector_type(8)))  __bf16 bf16x8;

// SFINAE hedge: mfma bf16 builtin takes v8bf16 on newer clang, v8i16 on older.
template <typename T, typename = void> struct mfma_takes : std::false_type {};
template <typename T>
struct mfma_takes<T, std::void_t<decltype(__builtin_amdgcn_mfma_f32_32x32x16_bf16(
    std::declval<T>(), std::declval<T>(), std::declval<floatx16>(), 0, 0, 0))>>
    : std::true_type {};

__device__ __forceinline__ floatx16 MFMA(short8 a, short8 b, floatx16 c) {
  if constexpr (mfma_takes<bf16x8>::value) {
    return __builtin_amdgcn_mfma_f32_32x32x16_bf16(
        __builtin_bit_cast(bf16x8, a), __builtin_bit_cast(bf16x8, b), c, 0, 0, 0);
  } else {
    return __builtin_amdgcn_mfma_f32_32x32x16_bf16(a, b, c, 0, 0, 0);
  }
}

__device__ __forceinline__ unsigned short bf16rne(float x) {
  unsigned int u = __float_as_uint(x);
  return (unsigned short)((u + 0x7FFFu + ((u >> 16) & 1u)) >> 16);
}

// ---------------------------------------------------------------------------
// Split W into bf16 hi/lo; pack bf16 hi/lo split of 0.5*||c||^2 per code.
__global__ void vq_prep(const float* __restrict__ w, float* __restrict__ ws) {
  const int tid = threadIdx.x;
  const int lane = tid & 63;
  const int k = blockIdx.x * 4 + (tid >> 6);
  const float v = w[(size_t)k * D_DIM + lane];
  const unsigned short h = bf16rne(v);
  const float hf = __uint_as_float((unsigned int)h << 16);
  const unsigned short l = bf16rne(v - hf);
  unsigned short* whi = (unsigned short*)(ws + WS_WHI);
  unsigned short* wlo = (unsigned short*)(ws + WS_WLO);
  whi[(size_t)k * D_DIM + lane] = h;
  wlo[(size_t)k * D_DIM + lane] = l;
  float s = v * v;
#pragma unroll
  for (int m = 32; m >= 1; m >>= 1) s += __shfl_xor(s, m);
  if (lane == 0) {
    const float cn2 = 0.5f * s;
    const unsigned short ch = bf16rne(cn2);
    const float chf = __uint_as_float((unsigned int)ch << 16);
    const unsigned short cl = bf16rne(cn2 - chf);
    ((unsigned int*)(ws + WS_CNP))[k] = (unsigned int)ch | ((unsigned int)cl << 16);
  }
}

// ---------------------------------------------------------------------------
// Fused split-bf16 MFMA distance + argmin + segment-sum scatter.
// Block = 8 waves x 32 tokens = 256 tokens; grid 256 = 1 block/CU, 2 waves/SIMD.
// B staged in LDS in 128-code double-buffered stages (2 x 32 KB): 64 barriers.
// Per chunk per wave: 13 MFMAs (12 for zh*wh+zl*wh+zh*wl, negated A, plus one
// folding 0.5*||c||^2 via A=1.0 at k-slots 0,1). d = 0.5*dist.
__global__ __launch_bounds__(512, 2) void vq_argmin(
    const float* __restrict__ z, float* __restrict__ ws)
{
  __shared__ __align__(16) unsigned short Wbuf[2][2][128 * 64]; // [buf][hi/lo]

  const int tid  = threadIdx.x;
  const int w    = tid >> 6;
  const int lane = tid & 63;
  const int m    = lane & 31;   // A row (token) / B col (code) in tile
  const int h    = lane >> 5;   // k-half selector
  const int tb   = blockIdx.x * 256;

  const unsigned short* whi = (const unsigned short*)(ws + WS_WHI);
  const unsigned short* wlo = (const unsigned short*)(ws + WS_WLO);
  const unsigned int*   cnp = (const unsigned int*)(ws + WS_CNP);

  // ---- A fragments: negated bf16 hi/lo split of this wave's 32 z rows ----
  short8 ah[4], al[4];
  float znorm = 0.f;
  {
    const float* zrow = z + (size_t)(tb + w * 32 + m) * D_DIM + 8 * h;
#pragma unroll
    for (int s4 = 0; s4 < 4; ++s4) {
      const float4 v0 = *(const float4*)(zrow + 16 * s4);
      const float4 v1 = *(const float4*)(zrow + 16 * s4 + 4);
      const float vals[8] = {v0.x, v0.y, v0.z, v0.w, v1.x, v1.y, v1.z, v1.w};
#pragma unroll
      for (int j = 0; j < 8; ++j) {
        const float x = vals[j];
        znorm += x * x;
        const float y = -x;
        const unsigned short hb = bf16rne(y);
        const float hf = __uint_as_float((unsigned int)hb << 16);
        const unsigned short lb = bf16rne(y - hf);
        ah[s4][j] = (short)hb;
        al[s4][j] = (short)lb;
      }
    }
    znorm += __shfl_xor(znorm, 32);   // other k-half of the same token row
  }

  // A operand for the cn-fold pass: bf16 1.0 at k-slots 0,1 on h==0 lanes
  short8 acn;
  {
    uint4 ab = {0u, 0u, 0u, 0u};
    ab.x = (h == 0) ? 0x3F803F80u : 0u;
    acn = __builtin_bit_cast(short8, ab);
  }
  const floatx16 kZero = {};

  float minv[16];
  int   mini[16];
#pragma unroll
  for (int r = 0; r < 16; ++r) { minv[r] = 3.4e38f; mini[r] = 0; }

  // ---- staging: one stage = 128 codes x 64 shorts = 1024 granules (16B)
  // per plane; 512 threads x 2 granules each. sl[0..1]=hi, sl[2..3]=lo.
  uint4 sl[4];
  auto stageLoad = [&](int s) {
    const unsigned short* bh8 = whi + (size_t)s * (128 * 64);
    const unsigned short* bl8 = wlo + (size_t)s * (128 * 64);
#pragma unroll
    for (int i = 0; i < 2; ++i) {
      sl[i]     = *(const uint4*)(bh8 + (size_t)(i * 512 + tid) * 8);
      sl[2 + i] = *(const uint4*)(bl8 + (size_t)(i * 512 + tid) * 8);
    }
  };
  auto stageWrite = [&](int cb) {
#pragma unroll
    for (int i = 0; i < 2; ++i) {
      const int idx = i * 512 + tid;          // granule index in [0,1024)
      const int r = idx >> 3, g = idx & 7;    // row in [0,128), granule in row
      const int off = r * 64 + ((g ^ (r & 7)) * 8);   // XOR-swizzled granule
      *(uint4*)&Wbuf[cb][0][off] = sl[i];
      *(uint4*)&Wbuf[cb][1][off] = sl[2 + i];
    }
  };

  stageLoad(0);
  stageWrite(0);
  __syncthreads();

  for (int s = 0; s < 64; ++s) {
    const int cb = s & 1;
    if (s + 1 < 64) stageLoad(s + 1);   // global -> regs, overlaps compute

    const unsigned short* bhb = &Wbuf[cb][0][0];
    const unsigned short* blb = &Wbuf[cb][1][0];

#pragma unroll 2
    for (int kc = 0; kc < 4; ++kc) {
      const int rowoff = (kc * 32 + m) * 64;
      short8 bh[4], bl[4];
#pragma unroll
      for (int s4 = 0; s4 < 4; ++s4) {
        const int off = rowoff + (((2 * s4 + h) ^ (m & 7)) * 8);
        bh[s4] = *(const short8*)(bhb + off);
        bl[s4] = *(const short8*)(blb + off);
      }
      const int code = s * 128 + kc * 32 + m;
      short8 bcn;
      {
        uint4 bb = {0u, 0u, 0u, 0u};
        bb.x = (h == 0) ? cnp[code] : 0u;
        bcn = __builtin_bit_cast(short8, bb);
      }
      floatx16 acc = MFMA(acn, bcn, kZero);   // acc = 0.5*||c||^2
#pragma unroll
      for (int s4 = 0; s4 < 4; ++s4) {
        acc = MFMA(ah[s4], bh[s4], acc);      // -= zh.ch
        acc = MFMA(al[s4], bh[s4], acc);      // -= zl.ch
        acc = MFMA(ah[s4], bl[s4], acc);      // -= zh.cl
      }
      // d = 0.5*(||c||^2 - 2 z.c); k ascending + strict '<' keeps first-min
#pragma unroll
      for (int r = 0; r < 16; ++r) {
        const float d = acc[r];
        const bool lt = d < minv[r];
        minv[r] = lt ? d : minv[r];
        mini[r] = lt ? code : mini[r];
      }
    }

    if (s + 1 < 64) stageWrite(cb ^ 1);
    __syncthreads();
  }

  // ---- reduce over the 32 lanes (cols) per row; first-index tie-break ----
#pragma unroll
  for (int r = 0; r < 16; ++r) {
#pragma unroll
    for (int mm = 1; mm < 32; mm <<= 1) {
      const float ov = __shfl_xor(minv[r], mm);
      const int   oi = __shfl_xor(mini[r], mm);
      if (ov < minv[r] || (ov == minv[r] && oi < mini[r])) { minv[r] = ov; mini[r] = oi; }
    }
  }

  // exchange arrays alias the (now idle) staging buffer
  float* mind_s = (float*)&Wbuf[0][0][0];
  int*   tok_s  = (int*)&Wbuf[0][0][0] + 256;

  // C/D layout: row = (r&3) + 8*(r>>2) + 4*h. One writer lane per row.
#pragma unroll
  for (int r = 0; r < 16; ++r) {
    const int mr = (r & 3) + 8 * (r >> 2) + 4 * h;
    if (m == mr) {
      tok_s[w * 32 + mr]  = mini[r];
      mind_s[w * 32 + mr] = 2.0f * minv[r] + znorm;   // full dist for qe
    }
  }
  __syncthreads();

  float* counts = ws + WS_COUNTS;
  float* embsum = ws + WS_EMBSUM;

  if (tid < 256) {
    float qe = mind_s[tid];
#pragma unroll
    for (int mm = 32; mm >= 1; mm >>= 1) qe += __shfl_xor(qe, mm);
    if ((tid & 63) == 0) atomicAdd(ws + WS_QE, qe);
    atomicAdd(&counts[tok_s[tid]], 1.0f);
  }

  // segment-sum of z: wave-coalesced atomics (64 consecutive floats/instr)
#pragma unroll 4
  for (int t = 0; t < 32; ++t) {
    const int row = w * 32 + t;
    const int tk = tok_s[row];
    const float zv = z[(size_t)(tb + row) * D_DIM + lane];
    atomicAdd(&embsum[(size_t)tk * D_DIM + lane], zv);
  }
}

// ---------------------------------------------------------------------------
__global__ void vq_finalize_cs(const float* __restrict__ cluster_size,
                               float* __restrict__ ws, float* __restrict__ out)
{
  const int k = blockIdx.x * 256 + threadIdx.x;
  const float ncs = cluster_size[k] * DECAY + OMD * ws[WS_COUNTS + k];
  out[OUT_CS + k] = ncs;
  float s = ncs;
#pragma unroll
  for (int m = 32; m >= 1; m >>= 1) s += __shfl_xor(s, m);
  __shared__ float part[4];
  if ((threadIdx.x & 63) == 0) part[threadIdx.x >> 6] = s;
  __syncthreads();
  if (threadIdx.x == 0) {
    atomicAdd(ws + WS_NSUM, part[0] + part[1] + part[2] + part[3]);
    if (blockIdx.x == 0) out[OUT_QE] = ws[WS_QE] * (1.0f / N_TOK);
  }
}

__global__ void vq_finalize_w(const float* __restrict__ embed_avg,
                              const float* __restrict__ ws, float* __restrict__ out)
{
  const int idx = blockIdx.x * 256 + threadIdx.x;
  const int k = idx >> 6;
  const float nea = embed_avg[idx] * DECAY + OMD * ws[WS_EMBSUM + idx];
  out[OUT_EA + idx] = nea;
  const float n = ws[WS_NSUM];
  const float ncs = out[OUT_CS + k];
  const float sm = (ncs + EPS) / (n + K_CODE * EPS) * n;
  out[OUT_W + idx] = nea / sm;
}

// ---------------------------------------------------------------------------
extern "C" void kernel_launch(void* const* d_in, const int* in_sizes, int n_in,
                              void* d_out, int out_size, void* d_ws, size_t ws_size,
                              hipStream_t stream) {
  const float* z  = (const float*)d_in[0];
  const float* w  = (const float*)d_in[1];
  const float* cs = (const float*)d_in[2];
  const float* ea = (const float*)d_in[3];
  float* out = (float*)d_out;
  float* ws  = (float*)d_ws;

  (void)hipMemsetAsync(d_ws, 0, (size_t)WS_ZERO * sizeof(float), stream);

  vq_prep<<<K_CODE / 4, 256, 0, stream>>>(w, ws);
  vq_argmin<<<N_TOK / 256, 512, 0, stream>>>(z, ws);
  vq_finalize_cs<<<K_CODE / 256, 256, 0, stream>>>(cs, ws, out);
  vq_finalize_w<<<K_CODE * D_DIM / 256, 256, 0, stream>>>(ea, ws, out);
}